// Round 2
// baseline (433.677 us; speedup 1.0000x reference)
//
#include <hip/hip_runtime.h>
#include <math.h>

#define NHQ 32
#define NKV 8
#define HD 64
#define QKV_DIM 3072   // (32 + 2*8) * 64
#define MODEL_DIM 2048
#define QSCALE 0.1803368801111204f   // 0.125 * log2(e): folds attn scale + exp2 conversion

typedef __attribute__((ext_vector_type(4))) float     f32x4;
typedef __attribute__((ext_vector_type(8))) _Float16  half8;
typedef __attribute__((ext_vector_type(4))) _Float16  half4v;
typedef __attribute__((ext_vector_type(2))) __fp16    fp16x2;
typedef __attribute__((ext_vector_type(4))) unsigned  uint32x4;

#define ASYNC_COPY16(g, l)                                                        \
    __builtin_amdgcn_global_load_lds(                                             \
        (const __attribute__((address_space(1))) void*)(g),                       \
        (__attribute__((address_space(3))) void*)(l), 16, 0, 0)

__device__ __forceinline__ float fast_exp2(float x)
{
#if __has_builtin(__builtin_amdgcn_exp2f)
    return __builtin_amdgcn_exp2f(x);
#else
    float r;
    asm volatile("v_exp_f32 %0, %1\ns_nop 0" : "=v"(r) : "v"(x));
    return r;
#endif
}

// ---------------------------------------------------------------------------
// fp32 -> f16 elementwise convert
// ---------------------------------------------------------------------------
__global__ __launch_bounds__(256)
void f32_to_f16_kernel(const float* __restrict__ src, _Float16* __restrict__ dst, int n4)
{
    int i = blockIdx.x * 256 + threadIdx.x;
    if (i < n4) {
        float4 v = ((const float4*)src)[i];
        half4v h = { (_Float16)v.x, (_Float16)v.y, (_Float16)v.z, (_Float16)v.w };
        ((half4v*)dst)[i] = h;
    }
}

// ---------------------------------------------------------------------------
// RoPE cos/sin table: tab[s*64 + fi] = cos, tab[s*64 + 32 + fi] = sin
// ---------------------------------------------------------------------------
__global__ __launch_bounds__(256)
void sincos_table_kernel(const int* __restrict__ pos, float* __restrict__ tab, int S)
{
    int i = blockIdx.x * 256 + threadIdx.x;
    if (i < S * 32) {
        int s = i >> 5, fi = i & 31;
        float p = (float)pos[s];
        float inv_freq = powf(150000.0f, -(float)fi * (1.0f / 32.0f));
        float ang = p * inv_freq;
        tab[s * 64 + fi]      = cosf(ang);
        tab[s * 64 + 32 + fi] = sinf(ang);
    }
}

// ---------------------------------------------------------------------------
// f16 MFMA GEMM: C[M,N] = A[M,K] @ W[N,K]^T + bias[N]
// MODE 0: fp32 out. MODE 1: f16 out. MODE 2: f16 out + fused RoPE epilogue.
// 3-stage ring pipeline, counted vmcnt(4), k-chunk XOR swizzle (see r1).
// ---------------------------------------------------------------------------
template<int MODE>
__global__ __launch_bounds__(256, 3)
void gemm_f16_mfma(const _Float16* __restrict__ A, const _Float16* __restrict__ W,
                   const float* __restrict__ bias, void* __restrict__ Cout,
                   const float* __restrict__ tab, int M, int N, int K, int S)
{
    __shared__ _Float16 As[3][128 * 32];
    __shared__ _Float16 Bs[3][128 * 32];

    const int t    = threadIdx.x;
    const int w    = t >> 6;
    const int lane = t & 63;
    const int quad = lane >> 4, l15 = lane & 15;
    const size_t m0 = (size_t)blockIdx.y * 128;
    const size_t n0 = (size_t)blockIdx.x * 128;
    const int wm = (w >> 1) * 64, wn = (w & 1) * 64;

    const int sr   = t >> 2;
    const int klog = ((t & 3) ^ ((sr >> 1) & 3)) * 8;
    const _Float16* ag0 = A + (m0 + sr) * K + klog;
    const _Float16* ag1 = A + (m0 + 64 + sr) * K + klog;
    const _Float16* bg0 = W + (n0 + sr) * K + klog;
    const _Float16* bg1 = W + (n0 + 64 + sr) * K + klog;

    const int xk8 = (quad ^ ((l15 >> 1) & 3)) * 8;

    f32x4 acc[4][4];
#pragma unroll
    for (int i = 0; i < 4; i++)
#pragma unroll
        for (int j = 0; j < 4; j++) acc[i][j] = (f32x4){0.f, 0.f, 0.f, 0.f};

    const int nt = K >> 5;   // K/32 tiles

#define STAGE_TILE(bi, kt_)                                         \
    do {                                                            \
        const int _k0 = (kt_) * 32;                                 \
        ASYNC_COPY16(ag0 + _k0, &As[bi][w * 512]);                  \
        ASYNC_COPY16(ag1 + _k0, &As[bi][2048 + w * 512]);           \
        ASYNC_COPY16(bg0 + _k0, &Bs[bi][w * 512]);                  \
        ASYNC_COPY16(bg1 + _k0, &Bs[bi][2048 + w * 512]);           \
    } while (0)

    STAGE_TILE(0, 0);
    STAGE_TILE(1, 1);
    asm volatile("s_waitcnt vmcnt(4)" ::: "memory");
    __builtin_amdgcn_s_barrier();
    __builtin_amdgcn_sched_barrier(0);

    int bc = 0;   // buffer holding tile kt
    for (int kt = 0; kt < nt; ++kt) {
        const _Float16* Ab = &As[bc][0];
        const _Float16* Bb = &Bs[bc][0];

        half8 af[4], bf[4];
#pragma unroll
        for (int i = 0; i < 4; i++) {
            af[i] = *(const half8*)(Ab + (wm + i * 16 + l15) * 32 + xk8);
            bf[i] = *(const half8*)(Bb + (wn + i * 16 + l15) * 32 + xk8);
        }

        if (kt + 2 < nt) {
            int bs = bc + 2; if (bs >= 3) bs -= 3;
            STAGE_TILE(bs, kt + 2);
        }

        __builtin_amdgcn_s_setprio(1);
#pragma unroll
        for (int i = 0; i < 4; i++)
#pragma unroll
            for (int j = 0; j < 4; j++)
                acc[i][j] = __builtin_amdgcn_mfma_f32_16x16x32_f16(af[i], bf[j], acc[i][j], 0, 0, 0);
        __builtin_amdgcn_s_setprio(0);

        if (kt + 1 < nt) {
            if (kt + 2 < nt) asm volatile("s_waitcnt vmcnt(4)" ::: "memory");
            else             asm volatile("s_waitcnt vmcnt(0)" ::: "memory");
            __builtin_amdgcn_s_barrier();
            __builtin_amdgcn_sched_barrier(0);
        }
        bc = bc + 1; if (bc == 3) bc = 0;
    }
#undef STAGE_TILE

    float bv[4];
#pragma unroll
    for (int j = 0; j < 4; j++) bv[j] = bias[n0 + wn + j * 16 + l15];

    const int ct = (int)(((n0 + wn) >> 6) % 6);

#pragma unroll
    for (int i = 0; i < 4; i++)
#pragma unroll
        for (int r = 0; r < 4; r++) {
            const size_t row = m0 + wm + i * 16 + quad * 4 + r;
            float v[4];
#pragma unroll
            for (int j = 0; j < 4; j++) v[j] = acc[i][j][r] + bv[j];

            if (MODE == 2 && ct != 5) {
                const float* tc = tab + (size_t)(row % S) * 64;
                const float ca = tc[l15],      sa = tc[32 + l15];
                const float cb = tc[16 + l15], sb = tc[48 + l15];
                const float qs = (ct < 4) ? QSCALE : 1.0f;
                const float n0v = v[0] * ca - v[2] * sa;
                const float n1v = v[1] * cb - v[3] * sb;
                const float n2v = v[2] * ca + v[0] * sa;
                const float n3v = v[3] * cb + v[1] * sb;
                v[0] = n0v * qs; v[1] = n1v * qs; v[2] = n2v * qs; v[3] = n3v * qs;
            }

            const size_t col = n0 + wn + l15;
#pragma unroll
            for (int j = 0; j < 4; j++) {
                if (MODE != 0) ((_Float16*)Cout)[row * N + col + j * 16] = (_Float16)v[j];
                else           ((float*)Cout)[row * N + col + j * 16] = v[j];
            }
        }
}

// ---------------------------------------------------------------------------
// V transpose: qkv V-chunks [token][g-chunk 64] -> vtg[(g*64 + d)*BS + token].
// ---------------------------------------------------------------------------
__global__ __launch_bounds__(256)
void transpose_v_kernel(const _Float16* __restrict__ qkv, _Float16* __restrict__ vtg, int BS)
{
    __shared__ _Float16 tile[64 * 72];
    const int t = threadIdx.x;
    const int tb = blockIdx.x * 64;
    const int g = blockIdx.y;
    const int voff = (g * 6 + 5) * 64;

    const int tok = t >> 2, dsub = (t & 3) * 16;
    const _Float16* src = qkv + (size_t)(tb + tok) * QKV_DIM + voff + dsub;
    *(half8*)&tile[tok * 72 + dsub]     = *(const half8*)(src);
    *(half8*)&tile[tok * 72 + dsub + 8] = *(const half8*)(src + 8);
    __syncthreads();

    const int d = t >> 2, tsub = (t & 3) * 16;
    half8 a, c;
#pragma unroll
    for (int i = 0; i < 8; i++) a[i] = tile[(tsub + i) * 72 + d];
#pragma unroll
    for (int i = 0; i < 8; i++) c[i] = tile[(tsub + 8 + i) * 72 + d];
    _Float16* dst = vtg + ((size_t)g * 64 + d) * BS + tb + tsub;
    *(half8*)dst       = a;
    *(half8*)(dst + 8) = c;
}

// ---------------------------------------------------------------------------
// MFMA flash attention, no-max exp2 softmax.
// Grid (S/32, NKV, B), 256 threads = 4 waves; wave w = q-head g*4+w, 32 q-rows.
// KVB=128 keys per barrier pair (2 barriers/tile, 16 tiles at S=2048).
// P never touches LDS: after swapped QK^T (mfma(K,Q)), the PV A-fragment
// permutation is realized in-register with v_permlane32_swap_b32 +
// v_permlane16_swap_b32 on the cvt_pkrtz-packed words (T12):
//   dest lane (quad,l15), frag pf[s][h] word layout {A.c0,A.c1,B.c0,B.c1}
//   where A,B come from src lanes ((quad&1)*2 + {0,1})*16 + l15 and
//   mt = h*2 + (quad>>1).  With X=u[s][h*2][c], Y=u[s][h*2+1][c]:
//     swap32(X,Y): X={X.r0,X.r1,Y.r0,Y.r1}, Y={X.r2,X.r3,Y.r2,Y.r3}
//     swap16(X,Y): X={X.r0,X.r2,Y.r0,Y.r2}=F_A, Y={X.r1,X.r3,Y.r1,Y.r3}=F_B
// L-row MFMA uses a constant ones B-fragment (1 iff l15==0) - no LDS rows.
// ---------------------------------------------------------------------------
#define KVB 128

__global__ __launch_bounds__(256, 4)
void attn_mfma(const _Float16* __restrict__ qkv, const _Float16* __restrict__ vtg,
               _Float16* __restrict__ out, int B, int S)
{
    __shared__ _Float16 Ks[KVB * 72];      // [key][d] stride 72
    __shared__ _Float16 VsT[64 * 136];     // [d][key] stride 136

    const int t = threadIdx.x, w = t >> 6, lane = t & 63;
    const int quad = lane >> 4, l15 = lane & 15;
    const int b = blockIdx.z, g = blockIdx.y;
    const int q0 = blockIdx.x * 32;
    const int qoff = (g * 6 + w) * 64;
    const int koff = (g * 6 + 4) * 64;

    // Q fragments: subtile s covers qrows q0+s*16 .. +16
    half8 qf[2][2];
#pragma unroll
    for (int s = 0; s < 2; s++) {
        const _Float16* qp = qkv + (size_t)(b * S + q0 + s * 16 + l15) * QKV_DIM + qoff;
        qf[s][0] = *(const half8*)(qp + quad * 8);
        qf[s][1] = *(const half8*)(qp + 32 + quad * 8);
    }

    // constant ones B-fragment for the L (row-sum) MFMA: col l15==0 only
    half8 lv;
    {
        const _Float16 one = (l15 == 0) ? (_Float16)1.0f : (_Float16)0.0f;
#pragma unroll
        for (int j = 0; j < 8; j++) lv[j] = one;
    }

    f32x4 O[2][4], L[2];
#pragma unroll
    for (int s = 0; s < 2; s++) {
        L[s] = (f32x4){0.f, 0.f, 0.f, 0.f};
#pragma unroll
        for (int dt = 0; dt < 4; dt++) O[s][dt] = (f32x4){0.f, 0.f, 0.f, 0.f};
    }

    // staging ownership (256 threads, 128-key tile)
    const int kst_tok = t >> 1;            // K: token row 0..127
    const int kst_d   = (t & 1) * 32;      // K: d half (4 x half8)
    const int vst_d   = t >> 3;            // V^T: d rows vst_d and 32+vst_d
    const int vst_sub = (t & 7) * 16;      // V^T: key sub-chunk of 16 (2 x half8)

    const _Float16* kbase  = qkv + (size_t)(b * S + kst_tok) * QKV_DIM + koff + kst_d;
    const _Float16* vbase0 = vtg + ((size_t)g * 64 + vst_d) * (size_t)(B * S) + b * S + vst_sub;
    const _Float16* vbase1 = vtg + ((size_t)g * 64 + 32 + vst_d) * (size_t)(B * S) + b * S + vst_sub;

    // preload tile 0
    half8 kr[4], vr[4];
#pragma unroll
    for (int i = 0; i < 4; i++) kr[i] = *(const half8*)(kbase + i * 8);
    vr[0] = *(const half8*)(vbase0);
    vr[1] = *(const half8*)(vbase0 + 8);
    vr[2] = *(const half8*)(vbase1);
    vr[3] = *(const half8*)(vbase1 + 8);

    for (int kt = 0; kt < S; kt += KVB) {
        // ---- commit staged registers to LDS ----
#pragma unroll
        for (int i = 0; i < 4; i++)
            *(half8*)&Ks[kst_tok * 72 + kst_d + i * 8] = kr[i];
        *(half8*)&VsT[vst_d * 136 + vst_sub]            = vr[0];
        *(half8*)&VsT[vst_d * 136 + vst_sub + 8]        = vr[1];
        *(half8*)&VsT[(32 + vst_d) * 136 + vst_sub]     = vr[2];
        *(half8*)&VsT[(32 + vst_d) * 136 + vst_sub + 8] = vr[3];
        __syncthreads();

        // ---- prefetch next tile (in flight during compute) ----
        if (kt + KVB < S) {
#pragma unroll
            for (int i = 0; i < 4; i++)
                kr[i] = *(const half8*)(kbase + (size_t)(kt + KVB) * QKV_DIM + i * 8);
            vr[0] = *(const half8*)(vbase0 + kt + KVB);
            vr[1] = *(const half8*)(vbase0 + kt + KVB + 8);
            vr[2] = *(const half8*)(vbase1 + kt + KVB);
            vr[3] = *(const half8*)(vbase1 + kt + KVB + 8);
        }

        // ---- two 64-key halves per staged tile ----
#pragma unroll
        for (int hb = 0; hb < 2; hb++) {
            const int kb = hb * 64;

            // S^T = K.Q^T : sacc[s][mt][r] = S^T[key=kb+mt*16+quad*4+r][qrow=s*16+l15]
            half8 kf[4][2];
#pragma unroll
            for (int mt = 0; mt < 4; mt++) {
                kf[mt][0] = *(const half8*)&Ks[(kb + mt * 16 + l15) * 72 + quad * 8];
                kf[mt][1] = *(const half8*)&Ks[(kb + mt * 16 + l15) * 72 + 32 + quad * 8];
            }
            f32x4 sacc[2][4];
#pragma unroll
            for (int s = 0; s < 2; s++)
#pragma unroll
                for (int mt = 0; mt < 4; mt++) {
                    f32x4 z = (f32x4){0.f, 0.f, 0.f, 0.f};
                    z = __builtin_amdgcn_mfma_f32_16x16x32_f16(kf[mt][0], qf[s][0], z, 0, 0, 0);
                    z = __builtin_amdgcn_mfma_f32_16x16x32_f16(kf[mt][1], qf[s][1], z, 0, 0, 0);
                    sacc[s][mt] = z;
                }

            // p = exp2(s), packed; in-register redistribution via permlane swaps
            unsigned u[2][4][2];
#pragma unroll
            for (int s = 0; s < 2; s++)
#pragma unroll
                for (int mt = 0; mt < 4; mt++) {
                    fp16x2 pa = __builtin_amdgcn_cvt_pkrtz(fast_exp2(sacc[s][mt][0]),
                                                           fast_exp2(sacc[s][mt][1]));
                    fp16x2 pb = __builtin_amdgcn_cvt_pkrtz(fast_exp2(sacc[s][mt][2]),
                                                           fast_exp2(sacc[s][mt][3]));
                    u[s][mt][0] = __builtin_bit_cast(unsigned, pa);
                    u[s][mt][1] = __builtin_bit_cast(unsigned, pb);
                }

            half8 pf[2][2];
#pragma unroll
            for (int s = 0; s < 2; s++)
#pragma unroll
                for (int h = 0; h < 2; h++) {
                    uint32x4 pw;
#pragma unroll
                    for (int c = 0; c < 2; c++) {
                        unsigned x = u[s][h * 2][c], y = u[s][h * 2 + 1][c];
                        asm("v_permlane32_swap_b32 %0, %1" : "+v"(x), "+v"(y));
                        asm("v_permlane16_swap_b32 %0, %1" : "+v"(x), "+v"(y));
                        pw[c]     = x;   // F_A: words for src quads (quad&1)*2
                        pw[2 + c] = y;   // F_B: words for src quads (quad&1)*2+1
                    }
                    pf[s][h] = __builtin_bit_cast(half8, pw);
                }

            // PV: O[qrow][d] += P.V ; L += P.ones
#pragma unroll
            for (int dt = 0; dt < 4; dt++) {
                half8 vv0 = *(const half8*)&VsT[(dt * 16 + l15) * 136 + kb + quad * 8];
                half8 vv1 = *(const half8*)&VsT[(dt * 16 + l15) * 136 + kb + 32 + quad * 8];
#pragma unroll
                for (int s = 0; s < 2; s++) {
                    O[s][dt] = __builtin_amdgcn_mfma_f32_16x16x32_f16(pf[s][0], vv0, O[s][dt], 0, 0, 0);
                    O[s][dt] = __builtin_amdgcn_mfma_f32_16x16x32_f16(pf[s][1], vv1, O[s][dt], 0, 0, 0);
                }
            }
#pragma unroll
            for (int s = 0; s < 2; s++) {
                L[s] = __builtin_amdgcn_mfma_f32_16x16x32_f16(pf[s][0], lv, L[s], 0, 0, 0);
                L[s] = __builtin_amdgcn_mfma_f32_16x16x32_f16(pf[s][1], lv, L[s], 0, 0, 0);
            }
        }
        __syncthreads();   // protect Ks/VsT before next staging
    }

    // ---- epilogue ----
    // L C/D layout: row=quad'*4+reg (qrow), col=l15' (ones-row index 0).
    // l for qrow = quad*4+r lives at lane quad*16 (l15'=0), reg r.
    const int hq = g * 4 + w;
#pragma unroll
    for (int s = 0; s < 2; s++)
#pragma unroll
        for (int r = 0; r < 4; r++) {
            const float lr = __shfl(L[s][r], lane & 48, 64);
            const float ir = 1.0f / lr;
            const size_t row = (size_t)(b * S + q0 + s * 16 + quad * 4 + r);
#pragma unroll
            for (int dt = 0; dt < 4; dt++)
                out[row * (NHQ * HD) + hq * 64 + dt * 16 + l15] = (_Float16)(O[s][dt][r] * ir);
        }
}

// ---------------------------------------------------------------------------
extern "C" void kernel_launch(void* const* d_in, const int* in_sizes, int n_in,
                              void* d_out, int out_size, void* d_ws, size_t ws_size,
                              hipStream_t stream)
{
    const float* hidden = (const float*)d_in[0];
    const int*   pos    = (const int*)d_in[1];
    const float* qkv_w  = (const float*)d_in[2];
    const float* qkv_b  = (const float*)d_in[3];
    const float* o_w    = (const float*)d_in[4];
    const float* o_b    = (const float*)d_in[5];
    float* out = (float*)d_out;

    const int S  = in_sizes[1];                 // 2048
    const int BS = in_sizes[0] / MODEL_DIM;     // 4096
    const int B  = BS / S;                      // 2

    _Float16* hA   = (_Float16*)d_ws;                      // [BS, 2048]
    _Float16* hW1  = hA   + (size_t)BS * MODEL_DIM;        // [3072, 2048]
    _Float16* hW2  = hW1  + (size_t)QKV_DIM * MODEL_DIM;   // [2048, 2048]
    _Float16* qkvh = hW2  + (size_t)MODEL_DIM * MODEL_DIM; // [BS, 3072]
    _Float16* atth = qkvh + (size_t)BS * QKV_DIM;          // [BS, 2048]
    float*    tab  = (float*)(atth + (size_t)BS * MODEL_DIM); // [S, 64]
    _Float16* vtg  = (_Float16*)(tab + (size_t)S * 64);    // [NKV*64, BS]

    // 0) fp32 -> f16 converts + rope table
    f32_to_f16_kernel<<<(BS * MODEL_DIM / 4 + 255) / 256, 256, 0, stream>>>(hidden, hA, BS * MODEL_DIM / 4);
    f32_to_f16_kernel<<<(QKV_DIM * MODEL_DIM / 4 + 255) / 256, 256, 0, stream>>>(qkv_w, hW1, QKV_DIM * MODEL_DIM / 4);
    f32_to_f16_kernel<<<(MODEL_DIM * MODEL_DIM / 4 + 255) / 256, 256, 0, stream>>>(o_w, hW2, MODEL_DIM * MODEL_DIM / 4);
    sincos_table_kernel<<<(S * 32 + 255) / 256, 256, 0, stream>>>(pos, tab, S);

    // 1) QKV projection with fused RoPE (+0.125*log2e on Q)
    gemm_f16_mfma<2><<<dim3(QKV_DIM / 128, BS / 128), 256, 0, stream>>>(
        hA, hW1, qkv_b, qkvh, tab, BS, QKV_DIM, MODEL_DIM, S);

    // 1b) V transpose -> vtg
    transpose_v_kernel<<<dim3(BS / 64, NKV), 256, 0, stream>>>(qkvh, vtg, BS);

    // 2) Attention -> atth [BS, 2048]
    attn_mfma<<<dim3(S / 32, NKV, B), 256, 0, stream>>>(qkvh, vtg, atth, B, S);

    // 3) Output projection (fp32 out)
    gemm_f16_mfma<0><<<dim3(MODEL_DIM / 128, BS / 128), 256, 0, stream>>>(
        atth, hW2, o_b, out, nullptr, BS, MODEL_DIM, MODEL_DIM, S);
}

// Round 3
// 314.893 us; speedup vs baseline: 1.3772x; 1.3772x over previous
//
#include <hip/hip_runtime.h>
#include <math.h>

#define NHQ 32
#define NKV 8
#define HD 64
#define QKV_DIM 3072   // (32 + 2*8) * 64
#define MODEL_DIM 2048
#define QSCALE 0.1803368801111204f   // 0.125 * log2(e): folds attn scale + exp2 conversion

typedef __attribute__((ext_vector_type(4))) float     f32x4;
typedef __attribute__((ext_vector_type(8))) _Float16  half8;
typedef __attribute__((ext_vector_type(4))) _Float16  half4v;
typedef __attribute__((ext_vector_type(2))) __fp16    fp16x2;
typedef __attribute__((ext_vector_type(4))) unsigned  uint32x4;

#define ASYNC_COPY16(g, l)                                                        \
    __builtin_amdgcn_global_load_lds(                                             \
        (const __attribute__((address_space(1))) void*)(g),                       \
        (__attribute__((address_space(3))) void*)(l), 16, 0, 0)

__device__ __forceinline__ float fast_exp2(float x)
{
#if __has_builtin(__builtin_amdgcn_exp2f)
    return __builtin_amdgcn_exp2f(x);
#else
    float r;
    asm volatile("v_exp_f32 %0, %1\ns_nop 0" : "=v"(r) : "v"(x));
    return r;
#endif
}

// ---------------------------------------------------------------------------
// fp32 -> f16 elementwise convert
// ---------------------------------------------------------------------------
__global__ __launch_bounds__(256)
void f32_to_f16_kernel(const float* __restrict__ src, _Float16* __restrict__ dst, int n4)
{
    int i = blockIdx.x * 256 + threadIdx.x;
    if (i < n4) {
        float4 v = ((const float4*)src)[i];
        half4v h = { (_Float16)v.x, (_Float16)v.y, (_Float16)v.z, (_Float16)v.w };
        ((half4v*)dst)[i] = h;
    }
}

// ---------------------------------------------------------------------------
// RoPE cos/sin table: tab[s*64 + fi] = cos, tab[s*64 + 32 + fi] = sin
// ---------------------------------------------------------------------------
__global__ __launch_bounds__(256)
void sincos_table_kernel(const int* __restrict__ pos, float* __restrict__ tab, int S)
{
    int i = blockIdx.x * 256 + threadIdx.x;
    if (i < S * 32) {
        int s = i >> 5, fi = i & 31;
        float p = (float)pos[s];
        float inv_freq = powf(150000.0f, -(float)fi * (1.0f / 32.0f));
        float ang = p * inv_freq;
        tab[s * 64 + fi]      = cosf(ang);
        tab[s * 64 + 32 + fi] = sinf(ang);
    }
}

// ---------------------------------------------------------------------------
// f16 MFMA GEMM: C[M,N] = A[M,K] @ W[N,K]^T + bias[N]
// MODE 0: fp32 out. MODE 1: f16 out. MODE 2: f16 out + fused RoPE epilogue.
// 3-stage ring pipeline, counted vmcnt(4), k-chunk XOR swizzle (see r1).
// ---------------------------------------------------------------------------
template<int MODE>
__global__ __launch_bounds__(256, 3)
void gemm_f16_mfma(const _Float16* __restrict__ A, const _Float16* __restrict__ W,
                   const float* __restrict__ bias, void* __restrict__ Cout,
                   const float* __restrict__ tab, int M, int N, int K, int S)
{
    __shared__ _Float16 As[3][128 * 32];
    __shared__ _Float16 Bs[3][128 * 32];

    const int t    = threadIdx.x;
    const int w    = t >> 6;
    const int lane = t & 63;
    const int quad = lane >> 4, l15 = lane & 15;
    const size_t m0 = (size_t)blockIdx.y * 128;
    const size_t n0 = (size_t)blockIdx.x * 128;
    const int wm = (w >> 1) * 64, wn = (w & 1) * 64;

    const int sr   = t >> 2;
    const int klog = ((t & 3) ^ ((sr >> 1) & 3)) * 8;
    const _Float16* ag0 = A + (m0 + sr) * K + klog;
    const _Float16* ag1 = A + (m0 + 64 + sr) * K + klog;
    const _Float16* bg0 = W + (n0 + sr) * K + klog;
    const _Float16* bg1 = W + (n0 + 64 + sr) * K + klog;

    const int xk8 = (quad ^ ((l15 >> 1) & 3)) * 8;

    f32x4 acc[4][4];
#pragma unroll
    for (int i = 0; i < 4; i++)
#pragma unroll
        for (int j = 0; j < 4; j++) acc[i][j] = (f32x4){0.f, 0.f, 0.f, 0.f};

    const int nt = K >> 5;   // K/32 tiles

#define STAGE_TILE(bi, kt_)                                         \
    do {                                                            \
        const int _k0 = (kt_) * 32;                                 \
        ASYNC_COPY16(ag0 + _k0, &As[bi][w * 512]);                  \
        ASYNC_COPY16(ag1 + _k0, &As[bi][2048 + w * 512]);           \
        ASYNC_COPY16(bg0 + _k0, &Bs[bi][w * 512]);                  \
        ASYNC_COPY16(bg1 + _k0, &Bs[bi][2048 + w * 512]);           \
    } while (0)

    STAGE_TILE(0, 0);
    STAGE_TILE(1, 1);
    asm volatile("s_waitcnt vmcnt(4)" ::: "memory");
    __builtin_amdgcn_s_barrier();
    __builtin_amdgcn_sched_barrier(0);

    int bc = 0;   // buffer holding tile kt
    for (int kt = 0; kt < nt; ++kt) {
        const _Float16* Ab = &As[bc][0];
        const _Float16* Bb = &Bs[bc][0];

        half8 af[4], bf[4];
#pragma unroll
        for (int i = 0; i < 4; i++) {
            af[i] = *(const half8*)(Ab + (wm + i * 16 + l15) * 32 + xk8);
            bf[i] = *(const half8*)(Bb + (wn + i * 16 + l15) * 32 + xk8);
        }

        if (kt + 2 < nt) {
            int bs = bc + 2; if (bs >= 3) bs -= 3;
            STAGE_TILE(bs, kt + 2);
        }

        __builtin_amdgcn_s_setprio(1);
#pragma unroll
        for (int i = 0; i < 4; i++)
#pragma unroll
            for (int j = 0; j < 4; j++)
                acc[i][j] = __builtin_amdgcn_mfma_f32_16x16x32_f16(af[i], bf[j], acc[i][j], 0, 0, 0);
        __builtin_amdgcn_s_setprio(0);

        if (kt + 1 < nt) {
            if (kt + 2 < nt) asm volatile("s_waitcnt vmcnt(4)" ::: "memory");
            else             asm volatile("s_waitcnt vmcnt(0)" ::: "memory");
            __builtin_amdgcn_s_barrier();
            __builtin_amdgcn_sched_barrier(0);
        }
        bc = bc + 1; if (bc == 3) bc = 0;
    }
#undef STAGE_TILE

    float bv[4];
#pragma unroll
    for (int j = 0; j < 4; j++) bv[j] = bias[n0 + wn + j * 16 + l15];

    const int ct = (int)(((n0 + wn) >> 6) % 6);

#pragma unroll
    for (int i = 0; i < 4; i++)
#pragma unroll
        for (int r = 0; r < 4; r++) {
            const size_t row = m0 + wm + i * 16 + quad * 4 + r;
            float v[4];
#pragma unroll
            for (int j = 0; j < 4; j++) v[j] = acc[i][j][r] + bv[j];

            if (MODE == 2 && ct != 5) {
                const float* tc = tab + (size_t)(row % S) * 64;
                const float ca = tc[l15],      sa = tc[32 + l15];
                const float cb = tc[16 + l15], sb = tc[48 + l15];
                const float qs = (ct < 4) ? QSCALE : 1.0f;
                const float n0v = v[0] * ca - v[2] * sa;
                const float n1v = v[1] * cb - v[3] * sb;
                const float n2v = v[2] * ca + v[0] * sa;
                const float n3v = v[3] * cb + v[1] * sb;
                v[0] = n0v * qs; v[1] = n1v * qs; v[2] = n2v * qs; v[3] = n3v * qs;
            }

            const size_t col = n0 + wn + l15;
#pragma unroll
            for (int j = 0; j < 4; j++) {
                if (MODE != 0) ((_Float16*)Cout)[row * N + col + j * 16] = (_Float16)v[j];
                else           ((float*)Cout)[row * N + col + j * 16] = v[j];
            }
        }
}

// ---------------------------------------------------------------------------
// V transpose: qkv V-chunks [token][g-chunk 64] -> vtg[(g*64 + d)*BS + token].
// ---------------------------------------------------------------------------
__global__ __launch_bounds__(256)
void transpose_v_kernel(const _Float16* __restrict__ qkv, _Float16* __restrict__ vtg, int BS)
{
    __shared__ _Float16 tile[64 * 72];
    const int t = threadIdx.x;
    const int tb = blockIdx.x * 64;
    const int g = blockIdx.y;
    const int voff = (g * 6 + 5) * 64;

    const int tok = t >> 2, dsub = (t & 3) * 16;
    const _Float16* src = qkv + (size_t)(tb + tok) * QKV_DIM + voff + dsub;
    *(half8*)&tile[tok * 72 + dsub]     = *(const half8*)(src);
    *(half8*)&tile[tok * 72 + dsub + 8] = *(const half8*)(src + 8);
    __syncthreads();

    const int d = t >> 2, tsub = (t & 3) * 16;
    half8 a, c;
#pragma unroll
    for (int i = 0; i < 8; i++) a[i] = tile[(tsub + i) * 72 + d];
#pragma unroll
    for (int i = 0; i < 8; i++) c[i] = tile[(tsub + 8 + i) * 72 + d];
    _Float16* dst = vtg + ((size_t)g * 64 + d) * BS + tb + tsub;
    *(half8*)dst       = a;
    *(half8*)(dst + 8) = c;
}

// ---------------------------------------------------------------------------
// MFMA flash attention, no-max exp2 softmax, register-prefetched staging.
// Grid (S/32, NKV, B), 256 threads = 4 waves; wave w = q-head g*4+w, 32 q-rows.
// KVB=64 (r1's proven staging layout / register budget).
// P never touches LDS (T12): after swapped QK^T (mfma(K,Q)), the PV A-fragment
// permutation is realized in-register with v_permlane32_swap_b32 +
// v_permlane16_swap_b32 on the cvt_pkrtz-packed words:
//   with X=u[s][h*2][c], Y=u[s][h*2+1][c]:
//     swap32(X,Y): X={X.r0,X.r1,Y.r0,Y.r1}, Y={X.r2,X.r3,Y.r2,Y.r3}
//     swap16(X,Y): X={X.r0,X.r2,Y.r0,Y.r2}=F_A, Y={X.r1,X.r3,Y.r1,Y.r3}=F_B
//   (functionally verified in r2: passed with identical absmax)
// L-row MFMA uses a constant ones B-fragment (1 iff l15==0) — no LDS rows.
// LDS: Ks 9.2KB + VsT 9.2KB = 18.4KB (was 39.4KB) -> LDS no longer caps occupancy.
// ---------------------------------------------------------------------------
__global__ __launch_bounds__(256)
void attn_mfma(const _Float16* __restrict__ qkv, const _Float16* __restrict__ vtg,
               _Float16* __restrict__ out, int B, int S)
{
    __shared__ _Float16 Ks[64 * 72];       // [key][d] stride 72
    __shared__ _Float16 VsT[64 * 72];      // [d][key] stride 72

    const int t = threadIdx.x, w = t >> 6, lane = t & 63;
    const int quad = lane >> 4, l15 = lane & 15;
    const int b = blockIdx.z, g = blockIdx.y;
    const int q0 = blockIdx.x * 32;
    const int qoff = (g * 6 + w) * 64;
    const int koff = (g * 6 + 4) * 64;

    // Q fragments: subtile s covers qrows q0+s*16 .. +16
    half8 qf[2][2];
#pragma unroll
    for (int s = 0; s < 2; s++) {
        const _Float16* qp = qkv + (size_t)(b * S + q0 + s * 16 + l15) * QKV_DIM + qoff;
        qf[s][0] = *(const half8*)(qp + quad * 8);
        qf[s][1] = *(const half8*)(qp + 32 + quad * 8);
    }

    // constant ones B-fragment for the L (row-sum) MFMA: col l15==0 only
    half8 lv;
    {
        const _Float16 one = (l15 == 0) ? (_Float16)1.0f : (_Float16)0.0f;
#pragma unroll
        for (int j = 0; j < 8; j++) lv[j] = one;
    }

    f32x4 O[2][4], L[2];
#pragma unroll
    for (int s = 0; s < 2; s++) {
        L[s] = (f32x4){0.f, 0.f, 0.f, 0.f};
#pragma unroll
        for (int dt = 0; dt < 4; dt++) O[s][dt] = (f32x4){0.f, 0.f, 0.f, 0.f};
    }

    // staging ownership (r1 layout)
    const int kst_tok = t >> 2;            // K: token row 0..63
    const int kst_d   = (t & 3) * 16;      // K: d chunk of 16
    const int vst_d   = t >> 3;            // V^T: d rows vst_d and 32+vst_d
    const int vst_sub = (t & 7) * 8;       // V^T: key sub-chunk of 8

    const _Float16* kbase  = qkv + (size_t)(b * S + kst_tok) * QKV_DIM + koff + kst_d;
    const _Float16* vbase0 = vtg + ((size_t)g * 64 + vst_d) * (size_t)(B * S) + b * S + vst_sub;
    const _Float16* vbase1 = vtg + ((size_t)g * 64 + 32 + vst_d) * (size_t)(B * S) + b * S + vst_sub;

    // preload tile 0
    half8 kr0 = *(const half8*)(kbase);
    half8 kr1 = *(const half8*)(kbase + 8);
    half8 vr0 = *(const half8*)(vbase0);
    half8 vr1 = *(const half8*)(vbase1);

    for (int kt = 0; kt < S; kt += 64) {
        // ---- commit staged registers to LDS ----
        *(half8*)&Ks[kst_tok * 72 + kst_d]         = kr0;
        *(half8*)&Ks[kst_tok * 72 + kst_d + 8]     = kr1;
        *(half8*)&VsT[vst_d * 72 + vst_sub]        = vr0;
        *(half8*)&VsT[(32 + vst_d) * 72 + vst_sub] = vr1;
        __syncthreads();

        // ---- prefetch next tile (in flight during compute) ----
        if (kt + 64 < S) {
            kr0 = *(const half8*)(kbase + (size_t)(kt + 64) * QKV_DIM);
            kr1 = *(const half8*)(kbase + (size_t)(kt + 64) * QKV_DIM + 8);
            vr0 = *(const half8*)(vbase0 + kt + 64);
            vr1 = *(const half8*)(vbase1 + kt + 64);
        }

        // ---- S^T = K.Q^T : sacc[s][mt][r] = S^T[key=mt*16+quad*4+r][qrow=s*16+l15]
        half8 kf[4][2];
#pragma unroll
        for (int mt = 0; mt < 4; mt++) {
            kf[mt][0] = *(const half8*)&Ks[(mt * 16 + l15) * 72 + quad * 8];
            kf[mt][1] = *(const half8*)&Ks[(mt * 16 + l15) * 72 + 32 + quad * 8];
        }

        half8 pf[2][2];
#pragma unroll
        for (int s = 0; s < 2; s++) {
            f32x4 sacc[4];
#pragma unroll
            for (int mt = 0; mt < 4; mt++) {
                f32x4 z = (f32x4){0.f, 0.f, 0.f, 0.f};
                z = __builtin_amdgcn_mfma_f32_16x16x32_f16(kf[mt][0], qf[s][0], z, 0, 0, 0);
                z = __builtin_amdgcn_mfma_f32_16x16x32_f16(kf[mt][1], qf[s][1], z, 0, 0, 0);
                sacc[mt] = z;
            }

            // p = exp2(s), packed; in-register redistribution via permlane swaps
            unsigned u[4][2];
#pragma unroll
            for (int mt = 0; mt < 4; mt++) {
                fp16x2 pa = __builtin_amdgcn_cvt_pkrtz(fast_exp2(sacc[mt][0]),
                                                       fast_exp2(sacc[mt][1]));
                fp16x2 pb = __builtin_amdgcn_cvt_pkrtz(fast_exp2(sacc[mt][2]),
                                                       fast_exp2(sacc[mt][3]));
                u[mt][0] = __builtin_bit_cast(unsigned, pa);
                u[mt][1] = __builtin_bit_cast(unsigned, pb);
            }

#pragma unroll
            for (int h = 0; h < 2; h++) {
                uint32x4 pw;
#pragma unroll
                for (int c = 0; c < 2; c++) {
                    unsigned x = u[h * 2][c], y = u[h * 2 + 1][c];
                    asm("v_permlane32_swap_b32 %0, %1" : "+v"(x), "+v"(y));
                    asm("v_permlane16_swap_b32 %0, %1" : "+v"(x), "+v"(y));
                    pw[c]     = x;   // F_A: words for src quads (quad&1)*2
                    pw[2 + c] = y;   // F_B: words for src quads (quad&1)*2+1
                }
                pf[s][h] = __builtin_bit_cast(half8, pw);
            }
        }

        // ---- PV: O[qrow][d] += P.V ; L += P.ones ----
#pragma unroll
        for (int dt = 0; dt < 4; dt++) {
            half8 vv0 = *(const half8*)&VsT[(dt * 16 + l15) * 72 + quad * 8];
            half8 vv1 = *(const half8*)&VsT[(dt * 16 + l15) * 72 + 32 + quad * 8];
#pragma unroll
            for (int s = 0; s < 2; s++) {
                O[s][dt] = __builtin_amdgcn_mfma_f32_16x16x32_f16(pf[s][0], vv0, O[s][dt], 0, 0, 0);
                O[s][dt] = __builtin_amdgcn_mfma_f32_16x16x32_f16(pf[s][1], vv1, O[s][dt], 0, 0, 0);
            }
        }
#pragma unroll
        for (int s = 0; s < 2; s++) {
            L[s] = __builtin_amdgcn_mfma_f32_16x16x32_f16(pf[s][0], lv, L[s], 0, 0, 0);
            L[s] = __builtin_amdgcn_mfma_f32_16x16x32_f16(pf[s][1], lv, L[s], 0, 0, 0);
        }
        __syncthreads();   // protect Ks/VsT before next staging
    }

    // ---- epilogue ----
    // L C/D layout: row=quad'*4+reg (qrow), col=l15' (ones-row index 0).
    // l for qrow = quad*4+r lives at lane quad*16 (l15'=0), reg r.
    const int hq = g * 4 + w;
#pragma unroll
    for (int s = 0; s < 2; s++)
#pragma unroll
        for (int r = 0; r < 4; r++) {
            const float lr = __shfl(L[s][r], lane & 48, 64);
            const float ir = 1.0f / lr;
            const size_t row = (size_t)(b * S + q0 + s * 16 + quad * 4 + r);
#pragma unroll
            for (int dt = 0; dt < 4; dt++)
                out[row * (NHQ * HD) + hq * 64 + dt * 16 + l15] = (_Float16)(O[s][dt][r] * ir);
        }
}

// ---------------------------------------------------------------------------
extern "C" void kernel_launch(void* const* d_in, const int* in_sizes, int n_in,
                              void* d_out, int out_size, void* d_ws, size_t ws_size,
                              hipStream_t stream)
{
    const float* hidden = (const float*)d_in[0];
    const int*   pos    = (const int*)d_in[1];
    const float* qkv_w  = (const float*)d_in[2];
    const float* qkv_b  = (const float*)d_in[3];
    const float* o_w    = (const float*)d_in[4];
    const float* o_b    = (const float*)d_in[5];
    float* out = (float*)d_out;

    const int S  = in_sizes[1];                 // 2048
    const int BS = in_sizes[0] / MODEL_DIM;     // 4096
    const int B  = BS / S;                      // 2

    _Float16* hA   = (_Float16*)d_ws;                      // [BS, 2048]
    _Float16* hW1  = hA   + (size_t)BS * MODEL_DIM;        // [3072, 2048]
    _Float16* hW2  = hW1  + (size_t)QKV_DIM * MODEL_DIM;   // [2048, 2048]
    _Float16* qkvh = hW2  + (size_t)MODEL_DIM * MODEL_DIM; // [BS, 3072]
    _Float16* atth = qkvh + (size_t)BS * QKV_DIM;          // [BS, 2048]
    float*    tab  = (float*)(atth + (size_t)BS * MODEL_DIM); // [S, 64]
    _Float16* vtg  = (_Float16*)(tab + (size_t)S * 64);    // [NKV*64, BS]

    // 0) fp32 -> f16 converts + rope table
    f32_to_f16_kernel<<<(BS * MODEL_DIM / 4 + 255) / 256, 256, 0, stream>>>(hidden, hA, BS * MODEL_DIM / 4);
    f32_to_f16_kernel<<<(QKV_DIM * MODEL_DIM / 4 + 255) / 256, 256, 0, stream>>>(qkv_w, hW1, QKV_DIM * MODEL_DIM / 4);
    f32_to_f16_kernel<<<(MODEL_DIM * MODEL_DIM / 4 + 255) / 256, 256, 0, stream>>>(o_w, hW2, MODEL_DIM * MODEL_DIM / 4);
    sincos_table_kernel<<<(S * 32 + 255) / 256, 256, 0, stream>>>(pos, tab, S);

    // 1) QKV projection with fused RoPE (+0.125*log2e on Q)
    gemm_f16_mfma<2><<<dim3(QKV_DIM / 128, BS / 128), 256, 0, stream>>>(
        hA, hW1, qkv_b, qkvh, tab, BS, QKV_DIM, MODEL_DIM, S);

    // 1b) V transpose -> vtg
    transpose_v_kernel<<<dim3(BS / 64, NKV), 256, 0, stream>>>(qkvh, vtg, BS);

    // 2) Attention -> atth [BS, 2048]
    attn_mfma<<<dim3(S / 32, NKV, B), 256, 0, stream>>>(qkvh, vtg, atth, B, S);

    // 3) Output projection (fp32 out)
    gemm_f16_mfma<0><<<dim3(MODEL_DIM / 128, BS / 128), 256, 0, stream>>>(
        atth, hW2, o_b, out, nullptr, BS, MODEL_DIM, MODEL_DIM, S);
}